// Round 14
// baseline (67.464 us; speedup 1.0000x reference)
//
#include <hip/hip_runtime.h>

#define BATCH 4096
#define SEQ   80
#define EMBED 100
#define UNITS 64
#define NTILE (BATCH / 16)      // 256 batch tiles of 16 rows
#define NBLK2 (NTILE / 2)       // 128 blocks, 2 full tiles per block (in-wave ILP)
#define NVOC  10000
#define NVWV  ((NVOC + 15) / 16)

typedef float f32x4  __attribute__((ext_vector_type(4)));
typedef short bf16x8 __attribute__((ext_vector_type(8)));

#define MFMA16 __builtin_amdgcn_mfma_f32_16x16x32_bf16

// ---- ws layout (bytes) ----
#define TAB_OFF 0u           // bf16 table[10000][64] = 1,280,000 B (L2-resident)
#define W1T_OFF 1280000u     // ushort[64*128]
#define U1T_OFF 1296384u     // ushort[64*64]
#define W2T_OFF 1304576u
#define U2T_OFF 1312768u

__device__ __forceinline__ unsigned f2bfu(float f) {
    union { float f; unsigned u; } x; x.f = f;
    return (x.u + 0x7fffu + ((x.u >> 16) & 1u)) >> 16;   // RNE
}
__device__ __forceinline__ unsigned cvtpk(float lo, float hi) {
    unsigned r;
    asm("v_cvt_pk_bf16_f32 %0, %1, %2" : "=v"(r) : "v"(lo), "v"(hi));
    return r;
}
__device__ __forceinline__ float bflo(unsigned u) {
    union { unsigned u; float f; } x; x.u = u << 16; return x.f;
}
__device__ __forceinline__ float bfhi(unsigned u) {
    union { unsigned u; float f; } x; x.u = u & 0xffff0000u; return x.f;
}
// branch-free exact-tails tanh: 1 - 2/(e^{2x}+1)
__device__ __forceinline__ float fast_tanh(float x) {
    float e = __builtin_amdgcn_exp2f(x * 2.8853900817779268f);
    float r = __builtin_amdgcn_rcpf(e + 1.0f);
    return __builtin_fmaf(-2.0f, r, 1.0f);
}

// ---------------------------------------------------------------------------
// miniprep: transposed bf16 weight tables (unchanged, verified).
// ---------------------------------------------------------------------------
__global__ __launch_bounds__(256) void miniprep_kernel(
    const float* __restrict__ W1, const float* __restrict__ U1,
    const float* __restrict__ W2, const float* __restrict__ U2,
    char* __restrict__ ws)
{
    ushort* w1t = (ushort*)(ws + W1T_OFF);
    ushort* u1t = (ushort*)(ws + U1T_OFF);
    ushort* w2t = (ushort*)(ws + W2T_OFF);
    ushort* u2t = (ushort*)(ws + U2T_OFF);
    const int i = blockIdx.x * 256 + threadIdx.x;
    if (i < 8192) {
        const int u = i >> 7, k = i & 127;
        w1t[i] = (k < EMBED) ? (ushort)f2bfu(W1[k * UNITS + u]) : (ushort)0;
    } else if (i < 12288) {
        const int j = i - 8192, u = j >> 6, k = j & 63;
        u1t[j] = (ushort)f2bfu(U1[k * UNITS + u]);
    } else if (i < 16384) {
        const int j = i - 12288, u = j >> 6, k = j & 63;
        w2t[j] = (ushort)f2bfu(W2[k * UNITS + u]);
    } else if (i < 20480) {
        const int j = i - 16384, u = j >> 6, k = j & 63;
        u2t[j] = (ushort)f2bfu(U2[k * UNITS + u]);
    }
}

// ---------------------------------------------------------------------------
// tableproj: table[v] = b1 + emb[v] @ W1 (unchanged, verified).
// ---------------------------------------------------------------------------
__global__ __launch_bounds__(256) void tableproj_kernel(
    const float* __restrict__ emb,
    const float* __restrict__ b1,
    const ushort* __restrict__ w1t,
    char* __restrict__ table)
{
    const int lane = threadIdx.x & 63;
    const int wid  = threadIdx.x >> 6;
    const int gw   = blockIdx.x * 4 + wid;
    if (gw >= NVWV) return;
    const int m15  = lane & 15;
    const int kgrp = lane >> 4;
    const int v    = gw * 16 + m15;
    const int vc   = v < NVOC ? v : NVOC - 1;

    bf16x8 aW1[4][4];
    #pragma unroll
    for (int mt = 0; mt < 4; ++mt)
        #pragma unroll
        for (int ks = 0; ks < 4; ++ks)
            aW1[mt][ks] = *(const bf16x8*)(w1t + (16 * mt + m15) * 128 + kgrp * 8 + 32 * ks);

    const float* rp = emb + (size_t)vc * EMBED;
    bf16x8 bf[4];
    #pragma unroll
    for (int ks = 0; ks < 3; ++ks) {
        f32x4 e0 = *(const f32x4*)(rp + kgrp * 8 + 32 * ks);
        f32x4 e1 = *(const f32x4*)(rp + kgrp * 8 + 32 * ks + 4);
        uint4 u;
        u.x = cvtpk(e0.x, e0.y); u.y = cvtpk(e0.z, e0.w);
        u.z = cvtpk(e1.x, e1.y); u.w = cvtpk(e1.z, e1.w);
        bf[ks] = *(bf16x8*)&u;
    }
    {
        uint4 u = {0u, 0u, 0u, 0u};
        if (kgrp == 0) {
            f32x4 e0 = *(const f32x4*)(rp + 96);
            u.x = cvtpk(e0.x, e0.y); u.y = cvtpk(e0.z, e0.w);
        }
        bf[3] = *(bf16x8*)&u;
    }

    f32x4 acc[4];
    #pragma unroll
    for (int mt = 0; mt < 4; ++mt)
        acc[mt] = *(const f32x4*)(b1 + 16 * mt + 4 * kgrp);
    #pragma unroll
    for (int ks = 0; ks < 4; ++ks)
        #pragma unroll
        for (int mt = 0; mt < 4; ++mt)
            acc[mt] = MFMA16(aW1[mt][ks], bf[ks], acc[mt], 0, 0, 0);

    #pragma unroll
    for (int mt = 0; mt < 4; ++mt) {
        uint2 q;
        q.x = cvtpk(acc[mt][0], acc[mt][1]);
        q.y = cvtpk(acc[mt][2], acc[mt][3]);
        *(uint2*)(table + (size_t)v * 128 + mt * 32 + kgrp * 8) = q;
    }
}

// ---------------------------------------------------------------------------
// rnn: 2-tile in-wave ILP. 128 blocks x 4 waves; each wave runs its 16-unit
// slice for TWO independent 16-row tiles in one interleaved stream.
// One barrier per phase covers both tiles. No duplicated work.
// ---------------------------------------------------------------------------
__global__ __launch_bounds__(256, 1) void rnn_kernel(
    const int*    __restrict__ tokens,
    const uint2*  __restrict__ table,    // [10000][16] uint2
    const ushort* __restrict__ u1t,
    const ushort* __restrict__ w2t,
    const ushort* __restrict__ u2t,
    const float*  __restrict__ b2,
    const float*  __restrict__ Wo,
    const float*  __restrict__ bo,
    float*        __restrict__ out)
{
    __shared__ __align__(16) char h1L[2][2][2048];   // [tile][buf][16b x 64u, swz]
    __shared__ __align__(16) char h2L[2][2][2048];
    __shared__ int   tokL[2][16][84];                // pad 84: conflict-free
    __shared__ float headp[2][4][16];

    const int lane = threadIdx.x & 63;
    const int w    = threadIdx.x >> 6;
    const int m15  = lane & 15;
    const int kgrp = lane >> 4;
    const int swz  = (m15 & 7) << 4;
    const int wg   = blockIdx.x;
    const int rowA = wg * 32 + m15;        // tile A row for this lane
    // tile B row = rowA + 16

    // zero h2[-1] (buf 0) for both tiles: 2*2048B = 256 uint4
    {
        uint4 z = {0u, 0u, 0u, 0u};
        ((uint4*)h2L[0][0])[threadIdx.x & 127] = z;     // covered twice, harmless
        ((uint4*)h2L[1][0])[threadIdx.x & 127] = z;
    }
    // preload both tiles' tokens (32 rows x 80) into LDS
    for (int i = threadIdx.x; i < 2 * 16 * SEQ; i += 256) {
        const int ti = i / (16 * SEQ);
        const int r  = (i / SEQ) & 15;
        const int t  = i - (ti * 16 + r) * SEQ;
        tokL[ti][r][t] = tokens[(size_t)(wg * 32 + ti * 16 + r) * SEQ + t];
    }

    const int urow = 16 * w + m15;
    bf16x8 aU1[2], aW2[2], aU2[2];
    #pragma unroll
    for (int ks = 0; ks < 2; ++ks) {
        aU1[ks] = *(const bf16x8*)(u1t + urow * 64 + kgrp * 8 + 32 * ks);
        aW2[ks] = *(const bf16x8*)(w2t + urow * 64 + kgrp * 8 + 32 * ks);
        aU2[ks] = *(const bf16x8*)(u2t + urow * 64 + kgrp * 8 + 32 * ks);
    }
    const int ubase = 16 * w + 4 * kgrp;
    const f32x4 b2c = *(const f32x4*)(b2 + ubase);

    // token -> table-fragment pipelines (slice: + w*4 + kgrp), per tile
    const int*   tokpA = tokens + (size_t)rowA * SEQ;
    const int*   tokpB = tokens + (size_t)(rowA + 16) * SEQ;
    const uint2* tabp  = table + w * 4 + kgrp;

    uint2 q0A = tabp[(size_t)tokpA[0] * 16];
    uint2 qAA = tabp[(size_t)tokpA[1] * 16];
    uint2 qBA = tabp[(size_t)tokpA[2] * 16];
    uint2 qCA = tabp[(size_t)tokpA[3] * 16];
    int  tokCA = tokpA[4];
    uint2 q0B = tabp[(size_t)tokpB[0] * 16];
    uint2 qAB = tabp[(size_t)tokpB[1] * 16];
    uint2 qBB = tabp[(size_t)tokpB[2] * 16];
    uint2 qCB = tabp[(size_t)tokpB[3] * 16];
    int  tokCB = tokpB[4];

    // prologue: h1[0] = tanh(xw[0]) for both tiles -> buf 0
    {
        float a0 = fast_tanh(bflo(q0A.x)), a1 = fast_tanh(bfhi(q0A.x));
        float a2 = fast_tanh(bflo(q0A.y)), a3 = fast_tanh(bfhi(q0A.y));
        float b0 = fast_tanh(bflo(q0B.x)), b1_ = fast_tanh(bfhi(q0B.x));
        float b2_ = fast_tanh(bflo(q0B.y)), b3 = fast_tanh(bfhi(q0B.y));
        uint2 pkA; pkA.x = cvtpk(a0, a1); pkA.y = cvtpk(a2, a3);
        uint2 pkB; pkB.x = cvtpk(b0, b1_); pkB.y = cvtpk(b2_, b3);
        *(uint2*)(h1L[0][0] + m15 * 128 + ((32 * w + 8 * kgrp) ^ swz)) = pkA;
        *(uint2*)(h1L[1][0] + m15 * 128 + ((32 * w + 8 * kgrp) ^ swz)) = pkB;
    }
    asm volatile("s_waitcnt lgkmcnt(0)" ::: "memory");
    __builtin_amdgcn_s_barrier();

    float dA0 = 0.f, dA1 = 0.f, dA2 = 0.f, dA3 = 0.f;   // h2 tile A
    float dB0 = 0.f, dB1 = 0.f, dB2 = 0.f, dB3 = 0.f;   // h2 tile B

#define LBAR() do { asm volatile("s_waitcnt lgkmcnt(0)" ::: "memory"); \
                    __builtin_amdgcn_s_barrier(); } while (0)
// Phase T, both tiles interleaved; ONE barrier.
#define PHASE2(T, P, Q)                                                            \
  {                                                                                \
    uint2 qDA = tabp[(size_t)tokCA * 16];                                          \
    uint2 qDB = tabp[(size_t)tokCB * 16];                                          \
    const int tn = ((T) + 5 < SEQ) ? (T) + 5 : SEQ - 1;                            \
    const int tokNA = tokL[0][m15][tn];                                            \
    const int tokNB = tokL[1][m15][tn];                                            \
    bf16x8 Ah1a = *(const bf16x8*)(h1L[0][P] + m15 * 128 + ((kgrp * 16     ) ^ swz)); \
    bf16x8 Ah1b = *(const bf16x8*)(h1L[0][P] + m15 * 128 + ((kgrp * 16 + 64) ^ swz)); \
    bf16x8 Bh1a = *(const bf16x8*)(h1L[1][P] + m15 * 128 + ((kgrp * 16     ) ^ swz)); \
    bf16x8 Bh1b = *(const bf16x8*)(h1L[1][P] + m15 * 128 + ((kgrp * 16 + 64) ^ swz)); \
    bf16x8 Ah2a = *(const bf16x8*)(h2L[0][P] + m15 * 128 + ((kgrp * 16     ) ^ swz)); \
    bf16x8 Ah2b = *(const bf16x8*)(h2L[0][P] + m15 * 128 + ((kgrp * 16 + 64) ^ swz)); \
    bf16x8 Bh2a = *(const bf16x8*)(h2L[1][P] + m15 * 128 + ((kgrp * 16     ) ^ swz)); \
    bf16x8 Bh2b = *(const bf16x8*)(h2L[1][P] + m15 * 128 + ((kgrp * 16 + 64) ^ swz)); \
    f32x4 d1A = {bflo(qAA.x), bfhi(qAA.x), bflo(qAA.y), bfhi(qAA.y)};              \
    f32x4 d1B = {bflo(qAB.x), bfhi(qAB.x), bflo(qAB.y), bfhi(qAB.y)};              \
    d1A = MFMA16(aU1[0], Ah1a, d1A, 0, 0, 0);                                      \
    d1B = MFMA16(aU1[0], Bh1a, d1B, 0, 0, 0);                                      \
    d1A = MFMA16(aU1[1], Ah1b, d1A, 0, 0, 0);                                      \
    d1B = MFMA16(aU1[1], Bh1b, d1B, 0, 0, 0);                                      \
    f32x4 cA = b2c, cB = b2c;                                                      \
    cA = MFMA16(aW2[0], Ah1a, cA, 0, 0, 0);                                        \
    cB = MFMA16(aW2[0], Bh1a, cB, 0, 0, 0);                                        \
    cA = MFMA16(aW2[1], Ah1b, cA, 0, 0, 0);                                        \
    cB = MFMA16(aW2[1], Bh1b, cB, 0, 0, 0);                                        \
    f32x4 eA = {0.f, 0.f, 0.f, 0.f}, eB = {0.f, 0.f, 0.f, 0.f};                    \
    eA = MFMA16(aU2[0], Ah2a, eA, 0, 0, 0);                                        \
    eB = MFMA16(aU2[0], Bh2a, eB, 0, 0, 0);                                        \
    eA = MFMA16(aU2[1], Ah2b, eA, 0, 0, 0);                                        \
    eB = MFMA16(aU2[1], Bh2b, eB, 0, 0, 0);                                        \
    float nA0 = fast_tanh(d1A[0]), nA1 = fast_tanh(d1A[1]);                        \
    float nA2 = fast_tanh(d1A[2]), nA3 = fast_tanh(d1A[3]);                        \
    float nB0 = fast_tanh(d1B[0]), nB1 = fast_tanh(d1B[1]);                        \
    float nB2 = fast_tanh(d1B[2]), nB3 = fast_tanh(d1B[3]);                        \
    dA0 = fast_tanh(cA[0] + eA[0]); dA1 = fast_tanh(cA[1] + eA[1]);                \
    dA2 = fast_tanh(cA[2] + eA[2]); dA3 = fast_tanh(cA[3] + eA[3]);                \
    dB0 = fast_tanh(cB[0] + eB[0]); dB1 = fast_tanh(cB[1] + eB[1]);                \
    dB2 = fast_tanh(cB[2] + eB[2]); dB3 = fast_tanh(cB[3] + eB[3]);                \
    {                                                                              \
        uint2 pk; pk.x = cvtpk(nA0, nA1); pk.y = cvtpk(nA2, nA3);                  \
        *(uint2*)(h1L[0][Q] + m15 * 128 + ((32 * w + 8 * kgrp) ^ swz)) = pk;       \
    }                                                                              \
    {                                                                              \
        uint2 pk; pk.x = cvtpk(nB0, nB1); pk.y = cvtpk(nB2, nB3);                  \
        *(uint2*)(h1L[1][Q] + m15 * 128 + ((32 * w + 8 * kgrp) ^ swz)) = pk;       \
    }                                                                              \
    {                                                                              \
        uint2 pk; pk.x = cvtpk(dA0, dA1); pk.y = cvtpk(dA2, dA3);                  \
        *(uint2*)(h2L[0][Q] + m15 * 128 + ((32 * w + 8 * kgrp) ^ swz)) = pk;       \
    }                                                                              \
    {                                                                              \
        uint2 pk; pk.x = cvtpk(dB0, dB1); pk.y = cvtpk(dB2, dB3);                  \
        *(uint2*)(h2L[1][Q] + m15 * 128 + ((32 * w + 8 * kgrp) ^ swz)) = pk;       \
    }                                                                              \
    LBAR();                                                                        \
    qAA = qBA; qBA = qCA; qCA = qDA; tokCA = tokNA;                                \
    qAB = qBB; qBB = qCB; qCB = qDB; tokCB = tokNB;                                \
  }

    for (int t = 0; t < SEQ; t += 2) {
        PHASE2(t,     0, 1)
        PHASE2(t + 1, 1, 0)
    }
#undef PHASE2
#undef LBAR

    // ---- head: out = sigmoid(h2[79] @ Wo + bo), both tiles ----
    const f32x4 woc = *(const f32x4*)(Wo + ubase);
    float pA = dA0 * woc[0] + dA1 * woc[1] + dA2 * woc[2] + dA3 * woc[3];
    float pB = dB0 * woc[0] + dB1 * woc[1] + dB2 * woc[2] + dB3 * woc[3];
    pA += __shfl_xor(pA, 16, 64); pA += __shfl_xor(pA, 32, 64);
    pB += __shfl_xor(pB, 16, 64); pB += __shfl_xor(pB, 32, 64);
    if (lane < 16) {
        headp[0][w][lane] = pA;
        headp[1][w][lane] = pB;
    }
    __syncthreads();
    if (threadIdx.x < 32) {
        const int ti = threadIdx.x >> 4, bi = threadIdx.x & 15;
        const float z = headp[ti][0][bi] + headp[ti][1][bi]
                      + headp[ti][2][bi] + headp[ti][3][bi] + bo[0];
        const float e = __builtin_amdgcn_exp2f(-z * 1.4426950408889634f);
        out[wg * 32 + ti * 16 + bi] = __builtin_amdgcn_rcpf(1.0f + e);
    }
}

extern "C" void kernel_launch(void* const* d_in, const int* in_sizes, int n_in,
                              void* d_out, int out_size, void* d_ws, size_t ws_size,
                              hipStream_t stream) {
    const int*   tokens = (const int*)  d_in[0];
    const float* emb    = (const float*)d_in[1];
    const float* W1     = (const float*)d_in[2];
    const float* U1     = (const float*)d_in[3];
    const float* b1     = (const float*)d_in[4];
    const float* W2     = (const float*)d_in[5];
    const float* U2     = (const float*)d_in[6];
    const float* b2     = (const float*)d_in[7];
    const float* Wo     = (const float*)d_in[8];
    const float* bo     = (const float*)d_in[9];
    float* out = (float*)d_out;
    char*  ws  = (char*)d_ws;

    miniprep_kernel<<<80, 256, 0, stream>>>(W1, U1, W2, U2, ws);
    tableproj_kernel<<<(NVWV + 3) / 4, 256, 0, stream>>>(
        emb, b1, (const ushort*)(ws + W1T_OFF), ws + TAB_OFF);
    rnn_kernel<<<NBLK2, 256, 0, stream>>>(
        tokens, (const uint2*)(ws + TAB_OFF),
        (const ushort*)(ws + U1T_OFF), (const ushort*)(ws + W2T_OFF),
        (const ushort*)(ws + U2T_OFF),
        b2, Wo, bo, out);
}

// Round 15
// 56.695 us; speedup vs baseline: 1.1900x; 1.1900x over previous
//
#include <hip/hip_runtime.h>

#define BATCH 4096
#define SEQ   80
#define EMBED 100
#define UNITS 64
#define NTILE (BATCH / 16)      // 256 batch tiles of 16 rows
#define NVOC  10000
#define NVWV  ((NVOC + 15) / 16)
#define NPAIR2 (SEQ / 2)        // 40 timestep pairs

typedef float f32x4  __attribute__((ext_vector_type(4)));
typedef short bf16x8 __attribute__((ext_vector_type(8)));

#define MFMA16 __builtin_amdgcn_mfma_f32_16x16x32_bf16

// ---- ws layout (bytes) ----
#define TAB_OFF 0u           // bf16 table[10000][64] = 1,280,000 B (L2-resident)
#define W1T_OFF 1280000u     // ushort[64*128]
#define U1T_OFF 1296384u     // ushort[64*64]
#define W2T_OFF 1304576u
#define U2T_OFF 1312768u
#define XW2_OFF 1320960u     // uint4[256*4*40*64] = 41,943,040 B (pair-packed)

__device__ __forceinline__ unsigned f2bfu(float f) {
    union { float f; unsigned u; } x; x.f = f;
    return (x.u + 0x7fffu + ((x.u >> 16) & 1u)) >> 16;   // RNE
}
__device__ __forceinline__ unsigned cvtpk(float lo, float hi) {
    unsigned r;
    asm("v_cvt_pk_bf16_f32 %0, %1, %2" : "=v"(r) : "v"(lo), "v"(hi));
    return r;
}
__device__ __forceinline__ float bflo(unsigned u) {
    union { unsigned u; float f; } x; x.u = u << 16; return x.f;
}
__device__ __forceinline__ float bfhi(unsigned u) {
    union { unsigned u; float f; } x; x.u = u & 0xffff0000u; return x.f;
}
// branch-free exact-tails tanh: 1 - 2/(e^{2x}+1)
__device__ __forceinline__ float fast_tanh(float x) {
    float e = __builtin_amdgcn_exp2f(x * 2.8853900817779268f);
    float r = __builtin_amdgcn_rcpf(e + 1.0f);
    return __builtin_fmaf(-2.0f, r, 1.0f);
}

// ---------------------------------------------------------------------------
// miniprep: transposed bf16 weight tables (verified).
// ---------------------------------------------------------------------------
__global__ __launch_bounds__(256) void miniprep_kernel(
    const float* __restrict__ W1, const float* __restrict__ U1,
    const float* __restrict__ W2, const float* __restrict__ U2,
    char* __restrict__ ws)
{
    ushort* w1t = (ushort*)(ws + W1T_OFF);
    ushort* u1t = (ushort*)(ws + U1T_OFF);
    ushort* w2t = (ushort*)(ws + W2T_OFF);
    ushort* u2t = (ushort*)(ws + U2T_OFF);
    const int i = blockIdx.x * 256 + threadIdx.x;
    if (i < 8192) {
        const int u = i >> 7, k = i & 127;
        w1t[i] = (k < EMBED) ? (ushort)f2bfu(W1[k * UNITS + u]) : (ushort)0;
    } else if (i < 12288) {
        const int j = i - 8192, u = j >> 6, k = j & 63;
        u1t[j] = (ushort)f2bfu(U1[k * UNITS + u]);
    } else if (i < 16384) {
        const int j = i - 12288, u = j >> 6, k = j & 63;
        w2t[j] = (ushort)f2bfu(W2[k * UNITS + u]);
    } else if (i < 20480) {
        const int j = i - 16384, u = j >> 6, k = j & 63;
        u2t[j] = (ushort)f2bfu(U2[k * UNITS + u]);
    }
}

// ---------------------------------------------------------------------------
// tableproj: table[v] = b1 + emb[v] @ W1 (verified).
// ---------------------------------------------------------------------------
__global__ __launch_bounds__(256) void tableproj_kernel(
    const float* __restrict__ emb,
    const float* __restrict__ b1,
    const ushort* __restrict__ w1t,
    char* __restrict__ table)
{
    const int lane = threadIdx.x & 63;
    const int wid  = threadIdx.x >> 6;
    const int gw   = blockIdx.x * 4 + wid;
    if (gw >= NVWV) return;
    const int m15  = lane & 15;
    const int kgrp = lane >> 4;
    const int v    = gw * 16 + m15;
    const int vc   = v < NVOC ? v : NVOC - 1;

    bf16x8 aW1[4][4];
    #pragma unroll
    for (int mt = 0; mt < 4; ++mt)
        #pragma unroll
        for (int ks = 0; ks < 4; ++ks)
            aW1[mt][ks] = *(const bf16x8*)(w1t + (16 * mt + m15) * 128 + kgrp * 8 + 32 * ks);

    const float* rp = emb + (size_t)vc * EMBED;
    bf16x8 bf[4];
    #pragma unroll
    for (int ks = 0; ks < 3; ++ks) {
        f32x4 e0 = *(const f32x4*)(rp + kgrp * 8 + 32 * ks);
        f32x4 e1 = *(const f32x4*)(rp + kgrp * 8 + 32 * ks + 4);
        uint4 u;
        u.x = cvtpk(e0.x, e0.y); u.y = cvtpk(e0.z, e0.w);
        u.z = cvtpk(e1.x, e1.y); u.w = cvtpk(e1.z, e1.w);
        bf[ks] = *(bf16x8*)&u;
    }
    {
        uint4 u = {0u, 0u, 0u, 0u};
        if (kgrp == 0) {
            f32x4 e0 = *(const f32x4*)(rp + 96);
            u.x = cvtpk(e0.x, e0.y); u.y = cvtpk(e0.z, e0.w);
        }
        bf[3] = *(bf16x8*)&u;
    }

    f32x4 acc[4];
    #pragma unroll
    for (int mt = 0; mt < 4; ++mt)
        acc[mt] = *(const f32x4*)(b1 + 16 * mt + 4 * kgrp);
    #pragma unroll
    for (int ks = 0; ks < 4; ++ks)
        #pragma unroll
        for (int mt = 0; mt < 4; ++mt)
            acc[mt] = MFMA16(aW1[mt][ks], bf[ks], acc[mt], 0, 0, 0);

    #pragma unroll
    for (int mt = 0; mt < 4; ++mt) {
        uint2 q;
        q.x = cvtpk(acc[mt][0], acc[mt][1]);
        q.y = cvtpk(acc[mt][2], acc[mt][3]);
        *(uint2*)(table + (size_t)v * 128 + mt * 32 + kgrp * 8) = q;
    }
}

// ---------------------------------------------------------------------------
// expand: xw2[tile][w][pk][lane] = {table[tokE], table[tokO]} slices.
// Block = tile; tokens staged in LDS once; per iter 2 L2 gathers + one
// coalesced 1KB uint4 store. No recurrence -> fully pipelined.
// ---------------------------------------------------------------------------
__global__ __launch_bounds__(256) void expand_kernel(
    const int*   __restrict__ tokens,
    const uint2* __restrict__ table,     // [10000][16] uint2
    uint4*       __restrict__ xw2)
{
    __shared__ int tokL[16][84];

    const int lane = threadIdx.x & 63;
    const int w    = threadIdx.x >> 6;
    const int m15  = lane & 15;
    const int kgrp = lane >> 4;
    const int tile = blockIdx.x;

    for (int i = threadIdx.x; i < 16 * SEQ; i += 256) {
        const int r = i / SEQ;
        const int t = i - r * SEQ;
        tokL[r][t] = tokens[(size_t)(tile * 16 + r) * SEQ + t];
    }
    __syncthreads();

    const uint2* tabp = table + w * 4 + kgrp;
    uint4* outp = xw2 + ((size_t)(tile * 4 + w)) * NPAIR2 * 64 + lane;

    #pragma unroll 4
    for (int pk = 0; pk < NPAIR2; ++pk) {
        const int tokE = tokL[m15][2 * pk];
        const int tokO = tokL[m15][2 * pk + 1];
        uint2 gE = tabp[(size_t)tokE * 16];
        uint2 gO = tabp[(size_t)tokO * 16];
        uint4 o; o.x = gE.x; o.y = gE.y; o.z = gO.x; o.w = gO.y;
        outp[(size_t)pk * 64] = o;
    }
}

// ---------------------------------------------------------------------------
// rnn: R8's verified lean scan; stream loads now ONE uint4 per two phases
// (pair-packed layout). 4 waves/block M-split, 256 blocks, 1 barrier/phase.
// ---------------------------------------------------------------------------
__global__ __launch_bounds__(256, 1) void rnn_kernel(
    const uint4*  __restrict__ xw2,
    const ushort* __restrict__ u1t,
    const ushort* __restrict__ w2t,
    const ushort* __restrict__ u2t,
    const float*  __restrict__ b2,
    const float*  __restrict__ Wo,
    const float*  __restrict__ bo,
    float*        __restrict__ out)
{
    __shared__ __align__(16) char h1L[2][2048];   // [buf][16b x 64u bf16, swz]
    __shared__ __align__(16) char h2L[2][2048];
    __shared__ float headp[4][16];

    const int lane = threadIdx.x & 63;
    const int w    = threadIdx.x >> 6;
    const int m15  = lane & 15;
    const int kgrp = lane >> 4;
    const int swz  = (m15 & 7) << 4;
    const int wg   = blockIdx.x;

    {
        uint4 z = {0u, 0u, 0u, 0u};
        if (threadIdx.x < 128) ((uint4*)h2L[0])[threadIdx.x] = z;
    }

    const int urow = 16 * w + m15;
    bf16x8 aU1[2], aW2[2], aU2[2];
    #pragma unroll
    for (int ks = 0; ks < 2; ++ks) {
        aU1[ks] = *(const bf16x8*)(u1t + urow * 64 + kgrp * 8 + 32 * ks);
        aW2[ks] = *(const bf16x8*)(w2t + urow * 64 + kgrp * 8 + 32 * ks);
        aU2[ks] = *(const bf16x8*)(u2t + urow * 64 + kgrp * 8 + 32 * ks);
    }
    const int ubase = 16 * w + 4 * kgrp;
    const f32x4 b2c = *(const f32x4*)(b2 + ubase);

    // pair-packed stream: pair pk at xwp[pk*64]; holds {xw[2pk], xw[2pk+1]}
    const uint4* xwp = xw2 + ((size_t)(wg * 4 + w)) * NPAIR2 * 64 + lane;
    uint4 r0 = xwp[0];
    uint4 r1 = xwp[64];
    uint4 r2 = xwp[2 * 64];

    // prologue: h1[0] = tanh(xw[0]) -> buf 0   (xw[0] = r0.xy)
    {
        float t0 = fast_tanh(bflo(r0.x)), t1 = fast_tanh(bfhi(r0.x));
        float t2 = fast_tanh(bflo(r0.y)), t3 = fast_tanh(bfhi(r0.y));
        uint2 pk; pk.x = cvtpk(t0, t1); pk.y = cvtpk(t2, t3);
        *(uint2*)(h1L[0] + m15 * 128 + ((32 * w + 8 * kgrp) ^ swz)) = pk;
    }
    asm volatile("s_waitcnt lgkmcnt(0)" ::: "memory");
    __builtin_amdgcn_s_barrier();

    float d2f0 = 0.f, d2f1 = 0.f, d2f2 = 0.f, d2f3 = 0.f;

#define LBAR() do { asm volatile("s_waitcnt lgkmcnt(0)" ::: "memory"); \
                    __builtin_amdgcn_s_barrier(); } while (0)
// One phase; (QX,QY) = packed bf16 xw[T+1]. Math identical to R8 (verified).
#define PHASE(QX, QY, P, Q)                                                      \
  {                                                                              \
    bf16x8 bh1a = *(const bf16x8*)(h1L[P] + m15 * 128 + ((kgrp * 16     ) ^ swz)); \
    bf16x8 bh1b = *(const bf16x8*)(h1L[P] + m15 * 128 + ((kgrp * 16 + 64) ^ swz)); \
    bf16x8 bh2a = *(const bf16x8*)(h2L[P] + m15 * 128 + ((kgrp * 16     ) ^ swz)); \
    bf16x8 bh2b = *(const bf16x8*)(h2L[P] + m15 * 128 + ((kgrp * 16 + 64) ^ swz)); \
    f32x4 d1 = {bflo(QX), bfhi(QX), bflo(QY), bfhi(QY)};                         \
    d1 = MFMA16(aU1[0], bh1a, d1, 0, 0, 0);                                      \
    d1 = MFMA16(aU1[1], bh1b, d1, 0, 0, 0);                                      \
    f32x4 dC = b2c;                                                              \
    dC = MFMA16(aW2[0], bh1a, dC, 0, 0, 0);                                      \
    dC = MFMA16(aW2[1], bh1b, dC, 0, 0, 0);                                      \
    f32x4 dD = {0.f, 0.f, 0.f, 0.f};                                             \
    dD = MFMA16(aU2[0], bh2a, dD, 0, 0, 0);                                      \
    dD = MFMA16(aU2[1], bh2b, dD, 0, 0, 0);                                      \
    float n0 = fast_tanh(d1[0]);                                                 \
    float n1 = fast_tanh(d1[1]);                                                 \
    float n2 = fast_tanh(d1[2]);                                                 \
    float n3 = fast_tanh(d1[3]);                                                 \
    d2f0 = fast_tanh(dC[0] + dD[0]);                                             \
    d2f1 = fast_tanh(dC[1] + dD[1]);                                             \
    d2f2 = fast_tanh(dC[2] + dD[2]);                                             \
    d2f3 = fast_tanh(dC[3] + dD[3]);                                             \
    {                                                                            \
        uint2 pk; pk.x = cvtpk(n0, n1); pk.y = cvtpk(n2, n3);                    \
        *(uint2*)(h1L[Q] + m15 * 128 + ((32 * w + 8 * kgrp) ^ swz)) = pk;        \
    }                                                                            \
    {                                                                            \
        uint2 pk; pk.x = cvtpk(d2f0, d2f1); pk.y = cvtpk(d2f2, d2f3);            \
        *(uint2*)(h2L[Q] + m15 * 128 + ((32 * w + 8 * kgrp) ^ swz)) = pk;        \
    }                                                                            \
    LBAR();                                                                      \
  }

    for (int k = 0; k < NPAIR2; ++k) {
        const int pn = (k + 3 < NPAIR2) ? k + 3 : NPAIR2 - 1;
        uint4 r3 = xwp[(size_t)pn * 64];
        PHASE(r0.z, r0.w, 0, 1)     // phase 2k   uses xw[2k+1]
        PHASE(r1.x, r1.y, 1, 0)     // phase 2k+1 uses xw[2k+2]
        r0 = r1; r1 = r2; r2 = r3;
    }
#undef PHASE
#undef LBAR

    // ---- head: out[b] = sigmoid(h2[79] @ Wo + bo) ----
    const f32x4 woc = *(const f32x4*)(Wo + ubase);
    float p = d2f0 * woc[0] + d2f1 * woc[1] + d2f2 * woc[2] + d2f3 * woc[3];
    p += __shfl_xor(p, 16, 64);
    p += __shfl_xor(p, 32, 64);
    if (lane < 16) headp[w][lane] = p;
    __syncthreads();
    if (threadIdx.x < 16) {
        const float z = headp[0][threadIdx.x] + headp[1][threadIdx.x]
                      + headp[2][threadIdx.x] + headp[3][threadIdx.x] + bo[0];
        const float e = __builtin_amdgcn_exp2f(-z * 1.4426950408889634f);
        out[wg * 16 + threadIdx.x] = __builtin_amdgcn_rcpf(1.0f + e);
    }
}

extern "C" void kernel_launch(void* const* d_in, const int* in_sizes, int n_in,
                              void* d_out, int out_size, void* d_ws, size_t ws_size,
                              hipStream_t stream) {
    const int*   tokens = (const int*)  d_in[0];
    const float* emb    = (const float*)d_in[1];
    const float* W1     = (const float*)d_in[2];
    const float* U1     = (const float*)d_in[3];
    const float* b1     = (const float*)d_in[4];
    const float* W2     = (const float*)d_in[5];
    const float* U2     = (const float*)d_in[6];
    const float* b2     = (const float*)d_in[7];
    const float* Wo     = (const float*)d_in[8];
    const float* bo     = (const float*)d_in[9];
    float* out = (float*)d_out;
    char*  ws  = (char*)d_ws;

    miniprep_kernel<<<80, 256, 0, stream>>>(W1, U1, W2, U2, ws);
    tableproj_kernel<<<(NVWV + 3) / 4, 256, 0, stream>>>(
        emb, b1, (const ushort*)(ws + W1T_OFF), ws + TAB_OFF);
    expand_kernel<<<NTILE, 256, 0, stream>>>(
        tokens, (const uint2*)(ws + TAB_OFF), (uint4*)(ws + XW2_OFF));
    rnn_kernel<<<NTILE, 256, 0, stream>>>(
        (const uint4*)(ws + XW2_OFF),
        (const ushort*)(ws + U1T_OFF), (const ushort*)(ws + W2T_OFF),
        (const ushort*)(ws + U2T_OFF),
        b2, Wo, bo, out);
}